// Round 4
// baseline (1161.727 us; speedup 1.0000x reference)
//
#include <hip/hip_runtime.h>
#include <hip/hip_bf16.h>

#define B_SZ 8
#define T_SZ 1024
#define D_IN 512
#define D_H  64
#define N_H  8

typedef __hip_bfloat16 bf16;

// ---------------------------------------------------------------------------
// K/V projection: P[b][h][t][d] = sum_i X[b][t][i] * W[i][d][h], bf16 out.
// grid: (T/128, 2*N_H, B), block 256. Tile 128 rows x 64 cols, 8x4 per thread.
// ws usage: Kb, Vb = 2 x 4M bf16 = 16 MB total.
// ---------------------------------------------------------------------------
__global__ __launch_bounds__(256) void proj_kv_kernel(
    const float* __restrict__ keys, const float* __restrict__ values,
    const float* __restrict__ Wk, const float* __restrict__ Wv,
    bf16* __restrict__ Kb, bf16* __restrict__ Vb)
{
    const int tid = threadIdx.x;
    const int t0  = blockIdx.x * 128;
    const int mat = blockIdx.y >> 3;   // 0:K 1:V
    const int h   = blockIdx.y & 7;
    const int b   = blockIdx.z;

    const float* X = mat ? values : keys;
    const float* W = mat ? Wv     : Wk;
    bf16*        P = mat ? Vb     : Kb;

    __shared__ float XsT[32 * 129];   // [k][r], +1 pad
    __shared__ float Ws[32 * 64];     // [k][d]

    const int tr = tid >> 4;          // 0..15
    const int tc = tid & 15;          // 0..15
    const int r0 = tr * 8, c0 = tc * 4;

    float acc[8][4];
    #pragma unroll
    for (int i = 0; i < 8; ++i)
        #pragma unroll
        for (int j = 0; j < 4; ++j) acc[i][j] = 0.f;

    const float4* X4 = (const float4*)X;
    const size_t  xbase4 = (size_t)(b * T_SZ + t0) * (D_IN / 4);

    for (int i0 = 0; i0 < D_IN; i0 += 32) {
        #pragma unroll
        for (int q = 0; q < 4; ++q) {            // 128x32 X tile, transposed
            int e = tid + q * 256;               // 0..1023 float4s
            int r = e >> 3, c = e & 7;
            float4 v = X4[xbase4 + (size_t)r * (D_IN / 4) + (i0 >> 2) + c];
            int k = 4 * c;
            XsT[(k + 0) * 129 + r] = v.x;
            XsT[(k + 1) * 129 + r] = v.y;
            XsT[(k + 2) * 129 + r] = v.z;
            XsT[(k + 3) * 129 + r] = v.w;
        }
        #pragma unroll
        for (int q = 0; q < 8; ++q) {            // 32x64 W tile (stride-8 gather)
            int e = tid + q * 256;
            int k = e >> 6, d = e & 63;
            Ws[k * 64 + d] = W[(size_t)(i0 + k) * (D_H * N_H) + d * N_H + h];
        }
        __syncthreads();
        #pragma unroll
        for (int k = 0; k < 32; ++k) {
            float x[8], w[4];
            #pragma unroll
            for (int rr = 0; rr < 8; ++rr) x[rr] = XsT[k * 129 + r0 + rr];
            #pragma unroll
            for (int cc = 0; cc < 4; ++cc) w[cc] = Ws[k * 64 + c0 + cc];
            #pragma unroll
            for (int rr = 0; rr < 8; ++rr)
                #pragma unroll
                for (int cc = 0; cc < 4; ++cc)
                    acc[rr][cc] += x[rr] * w[cc];
        }
        __syncthreads();
    }

    const size_t pbase = ((size_t)(b * N_H + h) * T_SZ + t0) * D_H;
    #pragma unroll
    for (int rr = 0; rr < 8; ++rr)
        #pragma unroll
        for (int cc = 0; cc < 4; ++cc)
            P[pbase + (size_t)(r0 + rr) * D_H + c0 + cc] =
                __float2bfloat16(acc[rr][cc]);
}

// ---------------------------------------------------------------------------
// Attention per (b, h, 64-query tile), with Q-projection FUSED.
// Phase 0: Qs[j][d] = sum_i queries[b,j0+j,i] * Wq[i,d,h]   (fp32, in LDS)
// Main:    flash loop over 32-key i-tiles with K/V from bf16 ws.
// Output: fp32, out[b][j][h*64+d].
// grid: (T/64, N_H, B), block 256.
// ---------------------------------------------------------------------------
__global__ __launch_bounds__(256) void attn_kernel(
    const float* __restrict__ queries, const float* __restrict__ Wq,
    const bf16* __restrict__ Kb, const bf16* __restrict__ Vb,
    const int* __restrict__ key_seq, float* __restrict__ out)
{
    const int tid = threadIdx.x;
    const int j0  = blockIdx.x * 64;
    const int h   = blockIdx.y;
    const int b   = blockIdx.z;

    __shared__ float Qs[64 * 65];
    __shared__ float Ks[32 * 65];   // reused as X^T stage in phase 0
    __shared__ float Vs[32 * 65];   // reused as W stage in phase 0
    __shared__ float S [32 * 65];

    // ---- Phase 0: Q projection (64x64, K=512, chunks of 32) ----
    {
        const int tr = tid >> 4, tc = tid & 15;
        const int qr0 = tr * 4, qc0 = tc * 4;
        float qa[4][4];
        #pragma unroll
        for (int i = 0; i < 4; ++i)
            #pragma unroll
            for (int j = 0; j < 4; ++j) qa[i][j] = 0.f;

        for (int i0 = 0; i0 < D_IN; i0 += 32) {
            __syncthreads();
            #pragma unroll
            for (int q = 0; q < 8; ++q) {        // queries^T: [k][r], stride 65
                int e = tid + q * 256;           // 64 rows x 32 k
                int r = e >> 5, k = e & 31;
                Ks[k * 65 + r] =
                    queries[(size_t)(b * T_SZ + j0 + r) * D_IN + i0 + k];
            }
            #pragma unroll
            for (int q = 0; q < 8; ++q) {        // Wq: [k][d], stride 65
                int e = tid + q * 256;
                int k = e >> 6, d = e & 63;
                Vs[k * 65 + d] =
                    Wq[(size_t)(i0 + k) * (D_H * N_H) + d * N_H + h];
            }
            __syncthreads();
            #pragma unroll
            for (int k = 0; k < 32; ++k) {
                float x[4], w[4];
                #pragma unroll
                for (int rr = 0; rr < 4; ++rr) x[rr] = Ks[k * 65 + qr0 + rr];
                #pragma unroll
                for (int cc = 0; cc < 4; ++cc) w[cc] = Vs[k * 65 + qc0 + cc];
                #pragma unroll
                for (int rr = 0; rr < 4; ++rr)
                    #pragma unroll
                    for (int cc = 0; cc < 4; ++cc)
                        qa[rr][cc] += x[rr] * w[cc];
            }
        }
        #pragma unroll
        for (int rr = 0; rr < 4; ++rr)
            #pragma unroll
            for (int cc = 0; cc < 4; ++cc)
                Qs[(qr0 + rr) * 65 + qc0 + cc] = qa[rr][cc];
        // Qs visibility + Ks/Vs reuse safety: main loop's first sync covers.
    }

    // ---- Main flash loop ----
    const int oj = tid >> 2;          // 0..63 (4 lanes per query row)
    const int d0 = (tid & 3) * 16;
    const int ti = tid & 15;          // 2 i's per thread
    const int tj = tid >> 4;          // 4 j's per thread

    const size_t bh = (size_t)(b * N_H + h) * T_SZ;

    float m = -1e30f, l = 0.f;
    float O[16];
    #pragma unroll
    for (int dd = 0; dd < 16; ++dd) O[dd] = 0.f;

    const int ntiles = j0 / 32 + 2;   // causal: only i <= j0+63 needed
    for (int it = 0; it < ntiles; ++it) {
        const int i0 = it * 32;
        __syncthreads();              // protect Ks/Vs/S from prior readers
        #pragma unroll
        for (int q = 0; q < 8; ++q) {
            int e = tid + q * 256;
            int i = e >> 6, d = e & 63;
            Ks[i * 65 + d] = __bfloat162float(Kb[(bh + i0 + i) * D_H + d]);
            Vs[i * 65 + d] = __bfloat162float(Vb[(bh + i0 + i) * D_H + d]);
        }
        __syncthreads();

        float s[2][4];
        #pragma unroll
        for (int ii = 0; ii < 2; ++ii)
            #pragma unroll
            for (int jj = 0; jj < 4; ++jj) s[ii][jj] = 0.f;

        #pragma unroll 16
        for (int d = 0; d < 64; ++d) {
            float k0 = Ks[(2 * ti)     * 65 + d];
            float k1 = Ks[(2 * ti + 1) * 65 + d];
            float q0 = Qs[(4 * tj + 0) * 65 + d];
            float q1 = Qs[(4 * tj + 1) * 65 + d];
            float q2 = Qs[(4 * tj + 2) * 65 + d];
            float q3 = Qs[(4 * tj + 3) * 65 + d];
            s[0][0] += k0 * q0; s[0][1] += k0 * q1;
            s[0][2] += k0 * q2; s[0][3] += k0 * q3;
            s[1][0] += k1 * q0; s[1][1] += k1 * q1;
            s[1][2] += k1 * q2; s[1][3] += k1 * q3;
        }

        const int pad0 = (key_seq[b * T_SZ + i0 + 2 * ti]     == -1);
        const int pad1 = (key_seq[b * T_SZ + i0 + 2 * ti + 1] == -1);
        #pragma unroll
        for (int ii = 0; ii < 2; ++ii) {
            const int ig  = i0 + 2 * ti + ii;
            const int pad = ii ? pad1 : pad0;
            #pragma unroll
            for (int jj = 0; jj < 4; ++jj) {
                const int jg = j0 + 4 * tj + jj;
                float v = s[ii][jj];
                if (ig > jg) v -= 1000.f;   // causal (mask added BEFORE scaling)
                if (pad)     v -= 1000.f;   // key padding
                S[(2 * ti + ii) * 65 + 4 * tj + jj] = v * 0.125f;  // /sqrt(64)
            }
        }
        __syncthreads();

        // online softmax update for this thread's query row oj
        float mt = -1e30f;
        #pragma unroll 8
        for (int i = 0; i < 32; ++i) mt = fmaxf(mt, S[i * 65 + oj]);
        const float mnew  = fmaxf(m, mt);
        const float alpha = __expf(m - mnew);
        l *= alpha;
        #pragma unroll
        for (int dd = 0; dd < 16; ++dd) O[dd] *= alpha;

        #pragma unroll 4
        for (int i = 0; i < 32; ++i) {
            const float p = __expf(S[i * 65 + oj] - mnew);
            l += p;
            #pragma unroll
            for (int dd = 0; dd < 16; ++dd)
                O[dd] += p * Vs[i * 65 + d0 + dd];
        }
        m = mnew;
    }

    const float inv = 1.f / l;
    float4* out4 = (float4*)(out +
        (size_t)(b * T_SZ + j0 + oj) * (N_H * D_H) + h * D_H + d0);
    #pragma unroll
    for (int v = 0; v < 4; ++v) {
        float4 o;
        o.x = O[4 * v + 0] * inv;
        o.y = O[4 * v + 1] * inv;
        o.z = O[4 * v + 2] * inv;
        o.w = O[4 * v + 3] * inv;
        out4[v] = o;
    }
}

// ---------------------------------------------------------------------------
extern "C" void kernel_launch(void* const* d_in, const int* in_sizes, int n_in,
                              void* d_out, int out_size, void* d_ws, size_t ws_size,
                              hipStream_t stream) {
    const float* keys    = (const float*)d_in[0];
    const float* queries = (const float*)d_in[1];
    const float* values  = (const float*)d_in[2];
    const float* Wk      = (const float*)d_in[3];
    const float* Wq      = (const float*)d_in[4];
    const float* Wv      = (const float*)d_in[5];
    const int*   key_seq = (const int*)d_in[6];

    const size_t per = (size_t)B_SZ * N_H * T_SZ * D_H;   // 4,194,304 elems
    bf16* Kb = (bf16*)d_ws;
    bf16* Vb = Kb + per;                                   // 16 MB total

    proj_kv_kernel<<<dim3(T_SZ / 128, 2 * N_H, B_SZ), 256, 0, stream>>>(
        keys, values, Wk, Wv, Kb, Vb);
    attn_kernel<<<dim3(T_SZ / 64, N_H, B_SZ), 256, 0, stream>>>(
        queries, Wq, Kb, Vb, key_seq, (float*)d_out);
}

// Round 5
// 183.880 us; speedup vs baseline: 6.3178x; 6.3178x over previous
//
#include <hip/hip_runtime.h>
#include <hip/hip_bf16.h>

#define B_SZ 8
#define T_SZ 1024
#define D_IN 512
#define D_H  64
#define N_H  8

typedef __hip_bfloat16 bf16;
using short8 = __attribute__((ext_vector_type(8))) short;
using short4v = __attribute__((ext_vector_type(4))) short;
using f32x4  = __attribute__((ext_vector_type(4))) float;

__device__ __forceinline__ unsigned short f2bf(float f) {
    union { __hip_bfloat16 b; unsigned short u; } c;
    c.b = __float2bfloat16(f);
    return c.u;
}

// ---------------------------------------------------------------------------
// Weight transpose: W[i(k)][d][h] fp32 -> Wt[mat][h][d][k] bf16 (1.5 MB).
// grid (512*512/256, 3). Coalesced reads; scattered bf16 writes (L2 absorbs).
// ---------------------------------------------------------------------------
__global__ __launch_bounds__(256) void wt_kernel(
    const float* __restrict__ Wk, const float* __restrict__ Wq,
    const float* __restrict__ Wv, unsigned short* __restrict__ Wt)
{
    const int mat = blockIdx.y;
    const float* W = (mat == 0) ? Wk : (mat == 1) ? Wq : Wv;
    int idx = blockIdx.x * 256 + threadIdx.x;      // over 512*512
    float v = W[idx];
    int k = idx >> 9, c = idx & 511;               // c = d*8 + h
    int h = c & 7, d = c >> 3;
    Wt[(((size_t)mat * 8 + h) * 64 + d) * 512 + k] = f2bf(v);
}

// ---------------------------------------------------------------------------
// MFMA projection: P[b][h][t][d] = sum_k X[b][t][k] * W[k][d][h], bf16 out.
// grid (8192/128, 3*8). Block: 128 rows x 64 cols, K=512 in chunks of 64.
// LDS rows padded to 72 bf16 (b128 frag reads bank-balanced).
// ---------------------------------------------------------------------------
__global__ __launch_bounds__(256) void proj_kernel(
    const float* __restrict__ keys, const float* __restrict__ queries,
    const float* __restrict__ values,
    const unsigned short* __restrict__ Wt, unsigned short* __restrict__ KQVb)
{
    const int tid = threadIdx.x;
    const int m0  = blockIdx.x * 128;
    const int mh  = blockIdx.y;
    const int mat = mh >> 3, h = mh & 7;

    const float* X = (mat == 0) ? keys : (mat == 1) ? queries : values;
    const unsigned short* WT = Wt + (size_t)mh * (64 * 512);   // [d][k]
    unsigned short* P = KQVb + (size_t)mat * ((size_t)B_SZ * N_H * T_SZ * D_H);

    __shared__ __align__(16) unsigned short Xst[128 * 72];
    __shared__ __align__(16) unsigned short Wst[64 * 72];

    const int wid = tid >> 6, lane = tid & 63;
    const int quad = lane >> 4, l15 = lane & 15;

    f32x4 acc[2][4];
    #pragma unroll
    for (int a = 0; a < 2; ++a)
        #pragma unroll
        for (int n = 0; n < 4; ++n) acc[a][n] = (f32x4){0.f, 0.f, 0.f, 0.f};

    const float4* X4 = (const float4*)X;

    for (int kc = 0; kc < 8; ++kc) {
        const int k0 = kc * 64;
        __syncthreads();
        // stage X: 128 rows x 64 k, fp32 -> bf16
        #pragma unroll
        for (int q2 = 0; q2 < 8; ++q2) {
            int e = tid + q2 * 256;                 // 0..2047 float4s
            int r = e >> 4, c4 = e & 15;
            float4 v = X4[(size_t)(m0 + r) * (D_IN / 4) + (k0 >> 2) + c4];
            short4v s = {(short)f2bf(v.x), (short)f2bf(v.y),
                         (short)f2bf(v.z), (short)f2bf(v.w)};
            *(short4v*)&Xst[r * 72 + c4 * 4] = s;
        }
        // stage Wt tile: 64 d x 64 k, b128 copies
        #pragma unroll
        for (int q2 = 0; q2 < 2; ++q2) {
            int e = tid + q2 * 256;                 // 0..511 short8 units
            int d = e >> 3, ch = e & 7;
            *(short8*)&Wst[d * 72 + ch * 8] =
                *(const short8*)&WT[(size_t)d * 512 + k0 + ch * 8];
        }
        __syncthreads();
        // MFMA: wave strip = rows [wid*32, wid*32+31]
        #pragma unroll
        for (int ic = 0; ic < 2; ++ic) {
            short8 a0 = *(const short8*)&Xst[(wid*32      + l15) * 72 + ic*32 + quad*8];
            short8 a1 = *(const short8*)&Xst[(wid*32 + 16 + l15) * 72 + ic*32 + quad*8];
            #pragma unroll
            for (int nt = 0; nt < 4; ++nt) {
                short8 bf = *(const short8*)&Wst[(nt*16 + l15) * 72 + ic*32 + quad*8];
                acc[0][nt] = __builtin_amdgcn_mfma_f32_16x16x32_bf16(a0, bf, acc[0][nt], 0, 0, 0);
                acc[1][nt] = __builtin_amdgcn_mfma_f32_16x16x32_bf16(a1, bf, acc[1][nt], 0, 0, 0);
            }
        }
    }

    // epilogue: D rows m = m0 + wid*32 + mt*16 + quad*4 + r; cols d = nt*16 + l15
    #pragma unroll
    for (int mt = 0; mt < 2; ++mt)
        #pragma unroll
        for (int r = 0; r < 4; ++r) {
            int m = m0 + wid * 32 + mt * 16 + quad * 4 + r;
            int bb = m >> 10, t = m & 1023;
            size_t base = (((size_t)(bb * N_H + h)) * T_SZ + t) * D_H;
            #pragma unroll
            for (int nt = 0; nt < 4; ++nt)
                P[base + nt * 16 + l15] = f2bf(acc[mt][r >= 0 ? mt : mt][0]), // placeholder avoided below
                P[base + nt * 16 + l15] = f2bf(acc[mt][nt][r]);
        }
}

// ---------------------------------------------------------------------------
// MFMA flash attention. grid (16, 8, 8), block 256 (4 waves).
// Wave w owns j-strip [j0 + 16w, +15]; per 64-key tile:
//   QK^T: A=K rows, B=Q rows (bt pattern) -> S[i][j], lane: j=l15, i=quad*4+r
//   softmax over i: register + 2x shfl_xor (j is lane-resident)
//   P -> wave-private LDS (stride 20, conflict-free) -> B-frag
//   PV:  A=V^T (transpose-staged, b128), D = O^T[d][j], alpha per j=l15.
// Output fp32 out[b][j][h*64+d].
// ---------------------------------------------------------------------------
__global__ __launch_bounds__(256) void attn_kernel(
    const unsigned short* __restrict__ Qb, const unsigned short* __restrict__ Kb,
    const unsigned short* __restrict__ Vb,
    const int* __restrict__ key_seq, float* __restrict__ out)
{
    const int tid = threadIdx.x;
    const int j0  = (int)(gridDim.x - 1 - blockIdx.x) * 64;  // longest-first
    const int h   = blockIdx.y;
    const int b   = blockIdx.z;
    const int wid = tid >> 6, lane = tid & 63;
    const int quad = lane >> 4, l15 = lane & 15;

    __shared__ __align__(16) unsigned short Qst[64 * 72];
    __shared__ __align__(16) unsigned short Kst[64 * 72];
    __shared__ __align__(16) unsigned short VTst[64 * 72];
    __shared__ __align__(16) unsigned short Pst[4][64 * 20];
    __shared__ float spadf[64];

    const size_t bh = (size_t)(b * N_H + h) * T_SZ;

    // stage Q tile once (b128 copies)
    #pragma unroll
    for (int q2 = 0; q2 < 2; ++q2) {
        int e = tid + q2 * 256;
        int j = e >> 3, ch = e & 7;
        *(short8*)&Qst[j * 72 + ch * 8] =
            *(const short8*)&Qb[(bh + j0 + j) * D_H + ch * 8];
    }
    __syncthreads();
    short8 qf0 = *(const short8*)&Qst[(wid * 16 + l15) * 72 +  0 + quad * 8];
    short8 qf1 = *(const short8*)&Qst[(wid * 16 + l15) * 72 + 32 + quad * 8];

    const int jg = j0 + wid * 16 + l15;

    float m = -1e30f, l = 0.f;
    f32x4 o0 = {0.f,0.f,0.f,0.f}, o1 = o0, o2 = o0, o3 = o0;

    const int ntiles = j0 / 64 + 1;
    for (int it64 = 0; it64 < ntiles; ++it64) {
        const int i0 = it64 * 64;
        __syncthreads();                       // prior readers done
        // stage K rows (b128)
        #pragma unroll
        for (int q2 = 0; q2 < 2; ++q2) {
            int e = tid + q2 * 256;
            int i = e >> 3, ch = e & 7;
            *(short8*)&Kst[i * 72 + ch * 8] =
                *(const short8*)&Kb[(bh + i0 + i) * D_H + ch * 8];
        }
        // stage V transposed: VT[d][i] (conflict-free scalar writes)
        #pragma unroll
        for (int q2 = 0; q2 < 2; ++q2) {
            int e = tid + q2 * 256;
            int i = e & 63, ch = e >> 6;       // ch 0..7
            short8 v = *(const short8*)&Vb[(bh + i0 + i) * D_H + ch * 8];
            #pragma unroll
            for (int c = 0; c < 8; ++c)
                VTst[(ch * 8 + c) * 72 + i] = (unsigned short)v[c];
        }
        if (tid < 64)
            spadf[tid] = (key_seq[b * T_SZ + i0 + tid] == -1) ? -1000.f : 0.f;
        __syncthreads();

        // ---- scores: S[i][j] ----
        float sv[16];
        #pragma unroll
        for (int it = 0; it < 4; ++it) {
            f32x4 s = {0.f, 0.f, 0.f, 0.f};
            short8 a0 = *(const short8*)&Kst[(it*16 + l15) * 72 +  0 + quad*8];
            s = __builtin_amdgcn_mfma_f32_16x16x32_bf16(a0, qf0, s, 0, 0, 0);
            short8 a1 = *(const short8*)&Kst[(it*16 + l15) * 72 + 32 + quad*8];
            s = __builtin_amdgcn_mfma_f32_16x16x32_bf16(a1, qf1, s, 0, 0, 0);
            #pragma unroll
            for (int r = 0; r < 4; ++r) {
                int iloc = it * 16 + quad * 4 + r;
                float v = s[r] + spadf[iloc];
                if (i0 + iloc > jg) v -= 1000.f;     // causal, pre-scale
                sv[it * 4 + r] = v * 0.125f;         // /sqrt(64)
            }
        }

        // ---- online softmax over i (per j = l15, reduce across quads) ----
        float mt = sv[0];
        #pragma unroll
        for (int k = 1; k < 16; ++k) mt = fmaxf(mt, sv[k]);
        mt = fmaxf(mt, __shfl_xor(mt, 16));
        mt = fmaxf(mt, __shfl_xor(mt, 32));
        const float mnew  = fmaxf(m, mt);
        const float alpha = __expf(m - mnew);
        float p[16], ls = 0.f;
        #pragma unroll
        for (int k = 0; k < 16; ++k) { p[k] = __expf(sv[k] - mnew); ls += p[k]; }
        ls += __shfl_xor(ls, 16);
        ls += __shfl_xor(ls, 32);
        l = l * alpha + ls;
        m = mnew;
        o0 *= alpha; o1 *= alpha; o2 *= alpha; o3 *= alpha;

        // ---- P -> wave-private LDS (row stride 20: banks 8*quad + l15/2) ----
        #pragma unroll
        for (int it = 0; it < 4; ++it)
            #pragma unroll
            for (int r = 0; r < 4; ++r)
                Pst[wid][(it * 16 + quad * 4 + r) * 20 + l15] =
                    f2bf(p[it * 4 + r]);

        // ---- P B-frags (column reads, 2-way max) ----
        short8 pf0, pf1;
        #pragma unroll
        for (int jj = 0; jj < 8; ++jj) {
            pf0[jj] = (short)Pst[wid][(     quad * 8 + jj) * 20 + l15];
            pf1[jj] = (short)Pst[wid][(32 + quad * 8 + jj) * 20 + l15];
        }

        // ---- PV: O^T[d][j] += V^T x P ----
        short8 a;
        a = *(const short8*)&VTst[(     l15) * 72 +      quad * 8];
        o0 = __builtin_amdgcn_mfma_f32_16x16x32_bf16(a, pf0, o0, 0, 0, 0);
        a = *(const short8*)&VTst[(     l15) * 72 + 32 + quad * 8];
        o0 = __builtin_amdgcn_mfma_f32_16x16x32_bf16(a, pf1, o0, 0, 0, 0);
        a = *(const short8*)&VTst[(16 + l15) * 72 +      quad * 8];
        o1 = __builtin_amdgcn_mfma_f32_16x16x32_bf16(a, pf0, o1, 0, 0, 0);
        a = *(const short8*)&VTst[(16 + l15) * 72 + 32 + quad * 8];
        o1 = __builtin_amdgcn_mfma_f32_16x16x32_bf16(a, pf1, o1, 0, 0, 0);
        a = *(const short8*)&VTst[(32 + l15) * 72 +      quad * 8];
        o2 = __builtin_amdgcn_mfma_f32_16x16x32_bf16(a, pf0, o2, 0, 0, 0);
        a = *(const short8*)&VTst[(32 + l15) * 72 + 32 + quad * 8];
        o2 = __builtin_amdgcn_mfma_f32_16x16x32_bf16(a, pf1, o2, 0, 0, 0);
        a = *(const short8*)&VTst[(48 + l15) * 72 +      quad * 8];
        o3 = __builtin_amdgcn_mfma_f32_16x16x32_bf16(a, pf0, o3, 0, 0, 0);
        a = *(const short8*)&VTst[(48 + l15) * 72 + 32 + quad * 8];
        o3 = __builtin_amdgcn_mfma_f32_16x16x32_bf16(a, pf1, o3, 0, 0, 0);
    }

    // epilogue: lane j = jg, d = dt*16 + quad*4 + r
    const float inv = 1.f / l;
    float* op = out + ((size_t)b * T_SZ + jg) * (N_H * D_H) + h * D_H + quad * 4;
    #pragma unroll
    for (int r = 0; r < 4; ++r) {
        op[ 0 + r] = o0[r] * inv;
        op[16 + r] = o1[r] * inv;
        op[32 + r] = o2[r] * inv;
        op[48 + r] = o3[r] * inv;
    }
}

// ---------------------------------------------------------------------------
extern "C" void kernel_launch(void* const* d_in, const int* in_sizes, int n_in,
                              void* d_out, int out_size, void* d_ws, size_t ws_size,
                              hipStream_t stream) {
    const float* keys    = (const float*)d_in[0];
    const float* queries = (const float*)d_in[1];
    const float* values  = (const float*)d_in[2];
    const float* Wk      = (const float*)d_in[3];
    const float* Wq      = (const float*)d_in[4];
    const float* Wv      = (const float*)d_in[5];
    const int*   key_seq = (const int*)d_in[6];

    const size_t per = (size_t)B_SZ * N_H * T_SZ * D_H;     // 4,194,304 elems
    unsigned short* KQVb = (unsigned short*)d_ws;            // K | Q | V bf16
    unsigned short* Kb = KQVb;
    unsigned short* Qb = KQVb + per;
    unsigned short* Vb = KQVb + 2 * per;
    unsigned short* Wt = KQVb + 3 * per;                     // 3*8*64*512 bf16

    wt_kernel<<<dim3(512 * 512 / 256, 3), 256, 0, stream>>>(Wk, Wq, Wv, Wt);
    proj_kernel<<<dim3((B_SZ * T_SZ) / 128, 3 * N_H), 256, 0, stream>>>(
        keys, queries, values, Wt, KQVb);
    attn_kernel<<<dim3(T_SZ / 64, N_H, B_SZ), 256, 0, stream>>>(
        Qb, Kb, Vb, key_seq, (float*)d_out);
}